// Round 3
// baseline (215.490 us; speedup 1.0000x reference)
//
#include <hip/hip_runtime.h>

#define D 640
#define HID 64
#define NITER 64
#define ROWS 4           // rows per block == waves per block
#define BLOCK 256

// ---- DPP wave64 reductions (VALU pipe only; no LDS-pipe swizzles) ----
// sum: old=0 + bound_ctrl=1 -> disabled/invalid lanes contribute 0 (identity)
#define DPP_ADD_STEP(v, ctrl, rmask)                                          \
    v += __builtin_bit_cast(float, __builtin_amdgcn_update_dpp(               \
             0, __builtin_bit_cast(int, v), ctrl, rmask, 0xf, true))
// max: old=src + bound_ctrl=0 -> disabled/invalid lanes yield own value (no-op)
#define DPP_MAX_STEP(v, ctrl, rmask)                                          \
    v = fmaxf(v, __builtin_bit_cast(float, __builtin_amdgcn_update_dpp(       \
             __builtin_bit_cast(int, v), __builtin_bit_cast(int, v),          \
             ctrl, rmask, 0xf, false)))

__device__ __forceinline__ float wave_sum_dpp(float v) {
    DPP_ADD_STEP(v, 0x111, 0xf);  // row_shr:1
    DPP_ADD_STEP(v, 0x112, 0xf);  // row_shr:2
    DPP_ADD_STEP(v, 0x114, 0xf);  // row_shr:4
    DPP_ADD_STEP(v, 0x118, 0xf);  // row_shr:8
    DPP_ADD_STEP(v, 0x142, 0xa);  // row_bcast:15 -> rows 1,3
    DPP_ADD_STEP(v, 0x143, 0xc);  // row_bcast:31 -> rows 2,3
    return __builtin_bit_cast(float,
        __builtin_amdgcn_readlane(__builtin_bit_cast(int, v), 63));
}
__device__ __forceinline__ float wave_max_dpp(float v) {
    DPP_MAX_STEP(v, 0x111, 0xf);
    DPP_MAX_STEP(v, 0x112, 0xf);
    DPP_MAX_STEP(v, 0x114, 0xf);
    DPP_MAX_STEP(v, 0x118, 0xf);
    DPP_MAX_STEP(v, 0x142, 0xa);
    DPP_MAX_STEP(v, 0x143, 0xc);
    return __builtin_bit_cast(float,
        __builtin_amdgcn_readlane(__builtin_bit_cast(int, v), 63));
}

__global__ __launch_bounds__(BLOCK) void dimmask_kernel(
    const float* __restrict__ x, const float* __restrict__ W1,
    const float* __restrict__ b1, const float* __restrict__ W2,
    const float* __restrict__ b2, float* __restrict__ out)
{
    constexpr float INV_T = 1.0f / 0.07f;
    constexpr float LOG2E = 1.4426950408889634f;
    constexpr float TEMP  = 0.07f;

    // lds_a: x rows for GEMM1, then reused for ht (x reloaded in epilogue)
    __shared__ float lds_a[ROWS][D];          // 10 KB
    __shared__ float lds_part[4][ROWS][HID];  // 4 KB
    __shared__ float lds_hid[ROWS][HID];      // 1 KB

    const int tid  = threadIdx.x;
    const int row0 = blockIdx.x * ROWS;

    // ---- stage x rows into LDS (coalesced float4) ----
    {
        const float4* xv  = (const float4*)(x + (size_t)row0 * D);
        float4*       lxv = (float4*)(&lds_a[0][0]);
        for (int i = tid; i < ROWS * D / 4; i += BLOCK) lxv[i] = xv[i];
    }
    __syncthreads();

    // ---- GEMM1: hid[r][k] = relu(sum_t x[r][t]*W1[t][k] + b1[k]) ----
    {
        const int k = tid & 63, c = tid >> 6;
        float acc[ROWS] = {0.f, 0.f, 0.f, 0.f};
        const int t0 = c * (D / 4);
#pragma unroll 4
        for (int t = t0; t < t0 + D / 4; ++t) {
            float w = W1[t * HID + k];
#pragma unroll
            for (int r = 0; r < ROWS; ++r) acc[r] += lds_a[r][t] * w;
        }
#pragma unroll
        for (int r = 0; r < ROWS; ++r) lds_part[c][r][k] = acc[r];
    }
    __syncthreads();
    {
        const int r = tid >> 6, k = tid & 63;
        float s = lds_part[0][r][k] + lds_part[1][r][k]
                + lds_part[2][r][k] + lds_part[3][r][k] + b1[k];
        lds_hid[r][k] = fmaxf(s, 0.f);
    }
    __syncthreads();

    // ---- GEMM2: ht[r][j] = -h*log2e/T  written over dead x in lds_a ----
    for (int j = tid; j < D; j += BLOCK) {
        float acc[ROWS] = {0.f, 0.f, 0.f, 0.f};
#pragma unroll 8
        for (int k = 0; k < HID; ++k) {
            float w = W2[k * D + j];
#pragma unroll
            for (int r = 0; r < ROWS; ++r) acc[r] += lds_hid[r][k] * w;
        }
        float bb = b2[j];
#pragma unroll
        for (int r = 0; r < ROWS; ++r)
            lds_a[r][j] = -(acc[r] + bb) * (LOG2E * INV_T);
    }
    __syncthreads();

    // ---- Phase B: one wave per row; w-domain, branchless, DPP reductions ----
    const int r = tid >> 6, l = tid & 63;
    float E[10], w[10];
    {
        float ht[10], hmax = -3.0e38f;
#pragma unroll
        for (int u = 0; u < 10; ++u) {
            ht[u] = lds_a[r][l + 64 * u];
            hmax = fmaxf(hmax, ht[u]);
        }
        hmax = wave_max_dpp(hmax);
#pragma unroll
        for (int u = 0; u < 10; ++u) {
            E[u] = __builtin_amdgcn_exp2f(ht[u] - hmax);  // <= 1, no overflow
            w[u] = 1.0f;
        }
    }

    for (int it = 0; it < NITER; ++it) {
        float e[10];
#pragma unroll
        for (int u = 0; u < 10; ++u) e[u] = w[u] * E[u];
        // explicit tree sum (depth 4) -- no serial fp chain
        float t0 = e[0] + e[1], t1 = e[2] + e[3], t2 = e[4] + e[5],
              t3 = e[6] + e[7], t4 = e[8] + e[9];
        float s = ((t0 + t1) + (t2 + t3)) + t4;
        s = wave_sum_dpp(s);
        float rs = __builtin_amdgcn_rcpf(s);
#pragma unroll
        for (int u = 0; u < 10; ++u) {
            float y  = e[u] * rs;                    // yhat in [0, ~1]
            float f  = 1.0f - y;
            float f2 = f * f, f4 = f2 * f2, f8 = f4 * f4;
            float f14 = f8 * f4 * f2;                // even powers: >= 0 always
            float p = fmaf(-0.0395668f, y, -0.0583090f);   // (1-y)^(2/7) Taylor
            p = fmaf(p, y, -0.1020408f);
            p = fmaf(p, y, -0.2857143f);
            p = fmaf(p, y, 1.0f);
            w[u] *= f14 * p;                         // (1-y)^(100/7)
        }
    }

    // ---- epilogue: m = w^T; out = m * x (x reloaded, coalesced, L2-hot) ----
    const float* xrow = x + (size_t)(row0 + r) * D;
    float* orow = out + (size_t)(row0 + r) * D;
#pragma unroll
    for (int u = 0; u < 10; ++u) {
        int j = l + 64 * u;
        float m = __builtin_amdgcn_exp2f(TEMP * __builtin_amdgcn_logf(w[u]));
        orow[j] = m * xrow[j];
    }
}

extern "C" void kernel_launch(void* const* d_in, const int* in_sizes, int n_in,
                              void* d_out, int out_size, void* d_ws, size_t ws_size,
                              hipStream_t stream) {
    const float* x  = (const float*)d_in[0];
    const float* W1 = (const float*)d_in[1];
    const float* b1 = (const float*)d_in[2];
    const float* W2 = (const float*)d_in[3];
    const float* b2 = (const float*)d_in[4];
    float* out = (float*)d_out;

    const int B = in_sizes[0] / D;            // 8192
    dim3 grid(B / ROWS), block(BLOCK);
    hipLaunchKernelGGL(dimmask_kernel, grid, block, 0, stream, x, W1, b1, W2, b2, out);
}

// Round 4
// 169.910 us; speedup vs baseline: 1.2683x; 1.2683x over previous
//
#include <hip/hip_runtime.h>

#define D 640
#define HID 64
#define NITER 64
#define ROWS 4           // rows per block == waves per block
#define BLOCK 256

typedef float v2f __attribute__((ext_vector_type(2)));

// ---- DPP wave64 reductions (VALU pipe only) ----
#define DPP_ADD_STEP(v, ctrl, rmask)                                          \
    v += __builtin_bit_cast(float, __builtin_amdgcn_update_dpp(               \
             0, __builtin_bit_cast(int, v), ctrl, rmask, 0xf, true))
#define DPP_MAX_STEP(v, ctrl, rmask)                                          \
    v = fmaxf(v, __builtin_bit_cast(float, __builtin_amdgcn_update_dpp(       \
             __builtin_bit_cast(int, v), __builtin_bit_cast(int, v),          \
             ctrl, rmask, 0xf, false)))

__device__ __forceinline__ float wave_sum_dpp(float v) {
    DPP_ADD_STEP(v, 0x111, 0xf);  // row_shr:1
    DPP_ADD_STEP(v, 0x112, 0xf);  // row_shr:2
    DPP_ADD_STEP(v, 0x114, 0xf);  // row_shr:4
    DPP_ADD_STEP(v, 0x118, 0xf);  // row_shr:8
    DPP_ADD_STEP(v, 0x142, 0xa);  // row_bcast:15
    DPP_ADD_STEP(v, 0x143, 0xc);  // row_bcast:31
    return __builtin_bit_cast(float,
        __builtin_amdgcn_readlane(__builtin_bit_cast(int, v), 63));
}
__device__ __forceinline__ float wave_max_dpp(float v) {
    DPP_MAX_STEP(v, 0x111, 0xf);
    DPP_MAX_STEP(v, 0x112, 0xf);
    DPP_MAX_STEP(v, 0x114, 0xf);
    DPP_MAX_STEP(v, 0x118, 0xf);
    DPP_MAX_STEP(v, 0x142, 0xa);
    DPP_MAX_STEP(v, 0x143, 0xc);
    return __builtin_bit_cast(float,
        __builtin_amdgcn_readlane(__builtin_bit_cast(int, v), 63));
}

__global__ __launch_bounds__(BLOCK) void dimmask_kernel(
    const float* __restrict__ x, const float* __restrict__ W1,
    const float* __restrict__ b1, const float* __restrict__ W2,
    const float* __restrict__ b2, float* __restrict__ out)
{
    constexpr float INV_T = 1.0f / 0.07f;
    constexpr float LOG2E = 1.4426950408889634f;
    constexpr float TEMP  = 0.07f;

    __shared__ float lds_a[ROWS][D];          // x rows, then ht
    __shared__ float lds_part[4][ROWS][HID];
    __shared__ float lds_hid[ROWS][HID];

    const int tid  = threadIdx.x;
    const int row0 = blockIdx.x * ROWS;

    // ---- stage x rows into LDS (coalesced float4) ----
    {
        const float4* xv  = (const float4*)(x + (size_t)row0 * D);
        float4*       lxv = (float4*)(&lds_a[0][0]);
        for (int i = tid; i < ROWS * D / 4; i += BLOCK) lxv[i] = xv[i];
    }
    __syncthreads();

    // ---- GEMM1: hid[r][k] = relu(sum_t x[r][t]*W1[t][k] + b1[k]) ----
    // ds_read_b128 for x (broadcast across lanes -> conflict-free)
    {
        const int k = tid & 63, c = tid >> 6;
        float acc[ROWS] = {0.f, 0.f, 0.f, 0.f};
        const int q0 = c * 40;                 // float4 index base (c*160/4)
#pragma unroll 4
        for (int q = q0; q < q0 + 40; ++q) {
            const int tb = q * 4;
            float w0 = W1[(tb + 0) * HID + k];
            float w1 = W1[(tb + 1) * HID + k];
            float w2 = W1[(tb + 2) * HID + k];
            float w3 = W1[(tb + 3) * HID + k];
#pragma unroll
            for (int r = 0; r < ROWS; ++r) {
                float4 xa = ((const float4*)&lds_a[r][0])[q];
                acc[r] += xa.x * w0 + xa.y * w1 + xa.z * w2 + xa.w * w3;
            }
        }
#pragma unroll
        for (int r = 0; r < ROWS; ++r) lds_part[c][r][k] = acc[r];
    }
    __syncthreads();
    {
        const int r = tid >> 6, k = tid & 63;
        float s = lds_part[0][r][k] + lds_part[1][r][k]
                + lds_part[2][r][k] + lds_part[3][r][k] + b1[k];
        lds_hid[r][k] = fmaxf(s, 0.f);
    }
    __syncthreads();

    // ---- GEMM2: ht[r][j] = -h*log2e/T over dead x in lds_a ----
    for (int j = tid; j < D; j += BLOCK) {
        float acc[ROWS] = {0.f, 0.f, 0.f, 0.f};
#pragma unroll 4
        for (int k4 = 0; k4 < HID / 4; ++k4) {
            const int kb = k4 * 4;
            float w0 = W2[(kb + 0) * D + j];
            float w1 = W2[(kb + 1) * D + j];
            float w2 = W2[(kb + 2) * D + j];
            float w3 = W2[(kb + 3) * D + j];
#pragma unroll
            for (int r = 0; r < ROWS; ++r) {
                float4 hh = ((const float4*)&lds_hid[r][0])[k4];
                acc[r] += hh.x * w0 + hh.y * w1 + hh.z * w2 + hh.w * w3;
            }
        }
        float bb = b2[j];
#pragma unroll
        for (int r = 0; r < ROWS; ++r)
            lds_a[r][j] = -(acc[r] + bb) * (LOG2E * INV_T);
    }
    __syncthreads();

    // ---- Phase B: one wave per row; packed f32, e-domain recurrence ----
    const int r = tid >> 6, l = tid & 63;
    v2f E2[5], e2[5];
    {
        float ht[10], hmax = -3.0e38f;
#pragma unroll
        for (int u = 0; u < 10; ++u) {
            ht[u] = lds_a[r][l + 64 * u];
            hmax = fmaxf(hmax, ht[u]);
        }
        hmax = wave_max_dpp(hmax);
#pragma unroll
        for (int u = 0; u < 5; ++u) {
            // pair u covers elements l+128u (.x) and l+128u+64 (.y)
            E2[u].x = __builtin_amdgcn_exp2f(fmaxf(ht[2 * u]     - hmax, -80.f));
            E2[u].y = __builtin_amdgcn_exp2f(fmaxf(ht[2 * u + 1] - hmax, -80.f));
            e2[u] = E2[u];   // w = 1
        }
    }

    const v2f Kc2 = {94.8979592f, 94.8979592f};     // k(k-1)/2, k=100/7
    const v2f Kc1 = {-14.2857143f, -14.2857143f};   // -k
    const v2f K1  = {1.0f, 1.0f};
    const v2f P4 = {-0.0395668f, -0.0395668f};      // (1-y)^(2/7) Taylor
    const v2f P3 = {-0.0583090f, -0.0583090f};
    const v2f P2 = {-0.1020408f, -0.1020408f};
    const v2f P1 = {-0.2857143f, -0.2857143f};

    for (int it = 0; it < NITER; ++it) {
        v2f t01 = e2[0] + e2[1], t23 = e2[2] + e2[3];
        v2f s2 = (t01 + t23) + e2[4];
        float s = s2.x + s2.y;
        s = wave_sum_dpp(s);
        float rs = __builtin_amdgcn_rcpf(s);
#pragma unroll
        for (int u = 0; u < 5; ++u) {
            v2f y = e2[u] * rs;
            if (__builtin_expect(__any(fmaxf(y.x, y.y) > 0.02f), 0)) {
                // exact-ish: (1-y)^14 * deg-4 Taylor of (1-y)^(2/7)
                v2f f  = K1 - y;
                v2f f2 = f * f, f4 = f2 * f2, f8 = f4 * f4;
                v2f f14 = f8 * f4 * f2;               // even powers: >= 0
                v2f p = __builtin_elementwise_fma(P4, y, P3);
                p = __builtin_elementwise_fma(p, y, P2);
                p = __builtin_elementwise_fma(p, y, P1);
                p = __builtin_elementwise_fma(p, y, K1);
                e2[u] *= f14 * p;
            } else {
                // deg-2 Taylor of (1-y)^(100/7), y <= 0.02
                v2f p = __builtin_elementwise_fma(Kc2, y, Kc1);
                p = __builtin_elementwise_fma(p, y, K1);
                e2[u] *= p;
            }
        }
    }

    // ---- epilogue: w = e/E, m = w^T, out = m*x ----
    const float* xrow = x + (size_t)(row0 + r) * D;
    float* orow = out + (size_t)(row0 + r) * D;
#pragma unroll
    for (int u = 0; u < 5; ++u) {
        float w0 = e2[u].x * __builtin_amdgcn_rcpf(E2[u].x);
        float w1 = e2[u].y * __builtin_amdgcn_rcpf(E2[u].y);
        float m0 = __builtin_amdgcn_exp2f(TEMP * __builtin_amdgcn_logf(w0));
        float m1 = __builtin_amdgcn_exp2f(TEMP * __builtin_amdgcn_logf(w1));
        int j0 = l + 128 * u, j1 = j0 + 64;
        orow[j0] = m0 * xrow[j0];
        orow[j1] = m1 * xrow[j1];
    }
}

extern "C" void kernel_launch(void* const* d_in, const int* in_sizes, int n_in,
                              void* d_out, int out_size, void* d_ws, size_t ws_size,
                              hipStream_t stream) {
    const float* x  = (const float*)d_in[0];
    const float* W1 = (const float*)d_in[1];
    const float* b1 = (const float*)d_in[2];
    const float* W2 = (const float*)d_in[3];
    const float* b2 = (const float*)d_in[4];
    float* out = (float*)d_out;

    const int B = in_sizes[0] / D;            // 8192
    dim3 grid(B / ROWS), block(BLOCK);
    hipLaunchKernelGGL(dimmask_kernel, grid, block, 0, stream, x, W1, b1, W2, b2, out);
}